// Round 2
// baseline (866.054 us; speedup 1.0000x reference)
//
#include <hip/hip_runtime.h>

#define NTOT 12288
#define NE   196608

// turn-local row r (0..2047) of turn t -> global node id
__device__ __forceinline__ int turn_row_map(int r, int t) {
  return (r >> 7) * 768 + t * 128 + (r & 127);
}

// ---------------- prep kernels ----------------
__global__ void k_feat(const float* __restrict__ emb, const float* __restrict__ nmask,
                       const int* __restrict__ nodeidx, float* __restrict__ h) {
  int i = blockIdx.x * blockDim.x + threadIdx.x;  // over NTOT*64 float4
  if (i >= NTOT * 64) return;
  int row = i >> 6;
  int src = nodeidx[row];
  float m = nmask[src];
  float4 v = ((const float4*)emb)[(size_t)src * 64 + (i & 63)];
  v.x *= m; v.y *= m; v.z *= m; v.w *= m;
  ((float4*)h)[i] = v;
}

__global__ void k_wcat(const float* __restrict__ Wz, const float* __restrict__ Uz,
                       const float* __restrict__ Wr, const float* __restrict__ Ur,
                       const float* __restrict__ Wn, const float* __restrict__ bz,
                       const float* __restrict__ br, const float* __restrict__ bn,
                       float* __restrict__ Wcat, float* __restrict__ bcat) {
  int i = blockIdx.x * blockDim.x + threadIdx.x;
  if (i >= 512 * 768) return;
  int k = i / 768, c3 = i - k * 768;
  int g = c3 >> 8, c = c3 & 255;
  if (i < 768) bcat[i] = (g == 0) ? bz[c] : (g == 1 ? br[c] : bn[c]);
  float v;
  if (k < 256) {
    const float* Wg = (g == 0) ? Wz : (g == 1 ? Wr : Wn);
    v = Wg[k * 256 + c];
  } else {
    v = (g == 0) ? Uz[(k - 256) * 256 + c] : (g == 1 ? Ur[(k - 256) * 256 + c] : 0.0f);
  }
  Wcat[i] = v;
}

__global__ void k_count(const int* __restrict__ edst, int* __restrict__ deg) {
  int e = blockIdx.x * blockDim.x + threadIdx.x;
  if (e < NE) atomicAdd(&deg[edst[e]], 1);
}

__global__ void k_scan(const int* __restrict__ deg, int* __restrict__ rowptr) {
  __shared__ int buf[256];
  __shared__ int base;
  int tid = threadIdx.x;
  if (tid == 0) { base = 0; rowptr[0] = 0; }
  __syncthreads();
  for (int chunk = 0; chunk < NTOT; chunk += 256) {
    buf[tid] = deg[chunk + tid];
    __syncthreads();
    for (int off = 1; off < 256; off <<= 1) {
      int v = (tid >= off) ? buf[tid - off] : 0;
      __syncthreads();
      buf[tid] += v;
      __syncthreads();
    }
    rowptr[chunk + tid + 1] = base + buf[tid];
    __syncthreads();
    if (tid == 255) base += buf[255];
    __syncthreads();
  }
}

__global__ void k_scatter(const int* __restrict__ esrc, const int* __restrict__ edst,
                          const int* __restrict__ rowptr, int* __restrict__ cursor,
                          int* __restrict__ col) {
  int e = blockIdx.x * blockDim.x + threadIdx.x;
  if (e >= NE) return;
  int d = edst[e];
  int pos = rowptr[d] + atomicAdd(&cursor[d], 1);
  col[pos] = esrc[e];
}

// ---------------- tiled fp32 GEMM, 64x64 tile, 256 thr, 4x4/thread ----------------
// MODE 0: full Wh = h @ W           (A=h rows direct, C=Wh rows direct, N=K=256)
// MODE 1: Wh rows of turn t         (A rows & C rows via turn_row_map, N=K=256)
// MODE 2: g1 = [msg|h_t] @ Wcat + b (M=2048,K=512,N=768; A cols<256 from msg, else h)
// MODE 3: GRU finish: acc=rh@Un; epilogue computes hn and writes h rows of turn t
template <int MODE>
__global__ void __launch_bounds__(256)
k_gemm(const float* __restrict__ A, const float* __restrict__ B, float* __restrict__ C,
       float* hbuf, const float* __restrict__ bias, const float* __restrict__ g1,
       int M, int N, int K, int t) {
  __shared__ float As[16][68];
  __shared__ float Bs[16][64];
  int tid = threadIdx.x;
  int bx = blockIdx.x, by = blockIdx.y;
  int tx = tid & 15, ty = tid >> 4;
  int arow = tid >> 2, kq = tid & 3;
  int gm = by * 64 + arow;
  float acc[4][4] = {};
  for (int k0 = 0; k0 < K; k0 += 16) {
    int k = k0 + kq * 4;
    float4 av;
    if constexpr (MODE == 0) {
      av = *(const float4*)(A + (size_t)gm * K + k);
    } else if constexpr (MODE == 1) {
      av = *(const float4*)(A + (size_t)turn_row_map(gm, t) * 256 + k);
    } else if constexpr (MODE == 2) {
      if (k < 256) av = *(const float4*)(A + (size_t)gm * 256 + k);
      else         av = *(const float4*)(hbuf + (size_t)turn_row_map(gm, t) * 256 + (k - 256));
    } else {
      av = *(const float4*)(A + (size_t)gm * K + k);
    }
    As[kq * 4 + 0][arow] = av.x;
    As[kq * 4 + 1][arow] = av.y;
    As[kq * 4 + 2][arow] = av.z;
    As[kq * 4 + 3][arow] = av.w;
    *(float4*)&Bs[ty][tx * 4] = *(const float4*)(B + (size_t)(k0 + ty) * N + bx * 64 + tx * 4);
    __syncthreads();
    float a4[4], b4[4];
#pragma unroll
    for (int kk = 0; kk < 16; kk++) {
#pragma unroll
      for (int i = 0; i < 4; i++) a4[i] = As[kk][ty * 4 + i];
#pragma unroll
      for (int j = 0; j < 4; j++) b4[j] = Bs[kk][tx * 4 + j];
#pragma unroll
      for (int i = 0; i < 4; i++)
#pragma unroll
        for (int j = 0; j < 4; j++) acc[i][j] += a4[i] * b4[j];
    }
    __syncthreads();
  }
  int row0 = by * 64 + ty * 4, col0 = bx * 64 + tx * 4;
#pragma unroll
  for (int i = 0; i < 4; i++) {
#pragma unroll
    for (int j = 0; j < 4; j++) {
      int r = row0 + i, c = col0 + j;
      if constexpr (MODE == 0) {
        C[(size_t)r * 256 + c] = acc[i][j];
      } else if constexpr (MODE == 1) {
        C[(size_t)turn_row_map(r, t) * 256 + c] = acc[i][j];
      } else if constexpr (MODE == 2) {
        C[(size_t)r * 768 + c] = acc[i][j] + bias[c];
      } else {  // MODE 3: GRU epilogue
        int v = turn_row_map(r, t);
        float zpre = g1[(size_t)r * 768 + c];
        float npre = g1[(size_t)r * 768 + 512 + c] + acc[i][j];
        float z = 1.f / (1.f + __expf(-zpre));
        float n = tanhf(npre);
        float hv = hbuf[(size_t)v * 256 + c];
        hbuf[(size_t)v * 256 + c] = (1.f - z) * hv + z * n;
      }
    }
  }
}

// es/ed per node: one 64-lane wave per row; lane l: head=l>>4, slot i=l&15 owns 4 ch
__global__ void k_esed(const float* __restrict__ Wh, const float* __restrict__ a_src,
                       const float* __restrict__ a_dst, float* __restrict__ es,
                       float* __restrict__ ed, int rows, int t, int full) {
  int w = (blockIdx.x * blockDim.x + threadIdx.x) >> 6;
  if (w >= rows) return;
  int lane = threadIdx.x & 63;
  int head = lane >> 4, i = lane & 15;
  int v = full ? w : turn_row_map(w, t);
  float4 x   = ((const float4*)Wh)[(size_t)v * 64 + head * 16 + i];
  float4 asv = ((const float4*)a_src)[head * 16 + i];
  float4 adv = ((const float4*)a_dst)[head * 16 + i];
  float ps = x.x * asv.x + x.y * asv.y + x.z * asv.z + x.w * asv.w;
  float pd = x.x * adv.x + x.y * adv.y + x.z * adv.z + x.w * adv.w;
  for (int m = 1; m < 16; m <<= 1) { ps += __shfl_xor(ps, m); pd += __shfl_xor(pd, m); }
  if (i == 0) { es[v * 4 + head] = ps; ed[v * 4 + head] = pd; }
}

// per-dst attention softmax + message; one wave per dst node.
// allnodes=0: waves are the 2048 turn-t dst nodes, msg stored at turn-local row.
// allnodes=1 (t=5): waves are all 12288 nodes; msg stored only where tid==5;
//                   attn_score written for all nodes (= 1/4 sum_h den/(den+1e-9)).
__global__ void k_attn(const int* __restrict__ rowptr, const int* __restrict__ col,
                       const float* __restrict__ es, const float* __restrict__ ed,
                       const float* __restrict__ Wh, float* __restrict__ msg,
                       float* __restrict__ score, int t, int allnodes) {
  int w = (blockIdx.x * blockDim.x + threadIdx.x) >> 6;
  int nwaves = allnodes ? NTOT : 2048;
  if (w >= nwaves) return;
  int lane = threadIdx.x & 63;
  int head = lane >> 4;
  int v, mrow, storemsg;
  if (allnodes) {
    v = w;
    int bt = v >> 7;          // b*6+t
    int tt = bt % 6;
    storemsg = (tt == t);
    mrow = (bt / 6) * 128 + (v & 127);
  } else {
    v = turn_row_map(w, t);
    mrow = w;
    storemsg = 1;
  }
  int rp0 = rowptr[v], rp1 = rowptr[v + 1];
  float edv = ed[v * 4 + head];
  float m = -1e30f;
  for (int j = rp0; j < rp1; j++) {
    int s = col[j];
    float lg = es[s * 4 + head] + edv;
    lg = lg >= 0.f ? lg : 0.2f * lg;
    m = fmaxf(m, lg);
  }
  float den = 0.f;
  float4 acc = make_float4(0.f, 0.f, 0.f, 0.f);
  for (int j = rp0; j < rp1; j++) {
    int s = col[j];
    float lg = es[s * 4 + head] + edv;
    lg = lg >= 0.f ? lg : 0.2f * lg;
    float wg = __expf(lg - m);
    den += wg;
    if (storemsg) {
      float4 x = ((const float4*)Wh)[(size_t)s * 64 + lane];
      acc.x += wg * x.x; acc.y += wg * x.y; acc.z += wg * x.z; acc.w += wg * x.w;
    }
  }
  float inv = 1.f / (den + 1e-9f);
  if (storemsg) {
    float4 o = make_float4(acc.x * inv, acc.y * inv, acc.z * inv, acc.w * inv);
    ((float4*)msg)[(size_t)mrow * 64 + lane] = o;
  }
  if (allnodes) {
    float val = den * inv;
    val += __shfl_xor(val, 16);
    val += __shfl_xor(val, 32);
    if (lane == 0) score[v] = 0.25f * val;
  }
}

__global__ void k_rh(const float* __restrict__ g1, const float* __restrict__ hbuf,
                     float* __restrict__ rh, int t) {
  int i = blockIdx.x * blockDim.x + threadIdx.x;  // 2048*256
  if (i >= 2048 * 256) return;
  int r = i >> 8, c = i & 255;
  float rpre = g1[(size_t)r * 768 + 256 + c];
  float rr = 1.f / (1.f + __expf(-rpre));
  rh[i] = rr * hbuf[(size_t)turn_row_map(r, t) * 256 + c];
}

// one block per (b,t): softmax over 128 node scores, then weighted mean of h
__global__ void k_pool(const float* __restrict__ score, const float* __restrict__ h,
                       float* __restrict__ pooled) {
  __shared__ float a[128];
  __shared__ float sinv;
  int bt = blockIdx.x;
  int base = bt * 128;
  int tid = threadIdx.x;
  if (tid < 128) a[tid] = score[base + tid];
  __syncthreads();
  if (tid == 0) {
    float mx = a[0];
    for (int n = 1; n < 128; n++) mx = fmaxf(mx, a[n]);
    float s = 0.f;
    for (int n = 0; n < 128; n++) { float e = __expf(a[n] - mx); a[n] = e; s += e; }
    sinv = 1.f / (s * 128.f);
  }
  __syncthreads();
  float acc = 0.f;
  for (int n = 0; n < 128; n++) acc += a[n] * h[(size_t)(base + n) * 256 + tid];
  pooled[bt * 256 + tid] = acc * sinv;
}

__global__ void k_out(const float* __restrict__ pooled, float* __restrict__ out) {
  int i = blockIdx.x * blockDim.x + threadIdx.x;  // 8192
  if (i >= 8192) return;
  int spk = i >> 12, b = (i >> 8) & 15, c = i & 255;
  float s = 0.f;
  for (int t = spk; t < 6; t += 2) s += pooled[(b * 6 + t) * 256 + c];
  out[i] = s;
}

extern "C" void kernel_launch(void* const* d_in, const int* in_sizes, int n_in,
                              void* d_out, int out_size, void* d_ws, size_t ws_size,
                              hipStream_t stream) {
  const float* emb    = (const float*)d_in[0];
  const float* nmask  = (const float*)d_in[1];
  const float* W      = (const float*)d_in[2];
  const float* a_src  = (const float*)d_in[3];
  const float* a_dst  = (const float*)d_in[4];
  const float* Wz     = (const float*)d_in[5];
  const float* Uz     = (const float*)d_in[6];
  const float* Wr     = (const float*)d_in[7];
  const float* Ur     = (const float*)d_in[8];
  const float* Wn     = (const float*)d_in[9];
  const float* Un     = (const float*)d_in[10];
  const float* bz     = (const float*)d_in[11];
  const float* br     = (const float*)d_in[12];
  const float* bn     = (const float*)d_in[13];
  const int* nodeidx  = (const int*)d_in[14];
  const int* esrc     = (const int*)d_in[15];
  const int* edst     = (const int*)d_in[16];
  float* out = (float*)d_out;

  // ---- workspace carve-out (rh aliases msg: msg is dead after k_gemm<2>) ----
  char* ws = (char*)d_ws;
  size_t off = 0;
  auto carve = [&](size_t bytes) { char* p = ws + off; off += (bytes + 255) & ~(size_t)255; return p; };
  float* h      = (float*)carve(NTOT * 256 * 4);      // 12.6 MB
  float* Wh     = (float*)carve(NTOT * 256 * 4);      // 12.6 MB
  float* es     = (float*)carve(NTOT * 4 * 4);
  float* ed     = (float*)carve(NTOT * 4 * 4);
  float* msg    = (float*)carve(2048 * 256 * 4);      // 2 MB (also rh)
  float* rh     = msg;                                 // alias: msg dead after k_gemm<2>
  float* g1     = (float*)carve(2048 * 768 * 4);      // 6 MB
  float* score  = (float*)carve(NTOT * 4);
  float* pooled = (float*)carve(96 * 256 * 4);
  float* Wcat   = (float*)carve(512 * 768 * 4);       // 1.5 MB
  float* bcat   = (float*)carve(768 * 4);
  int*   deg    = (int*)carve(NTOT * 4);
  int*   cursor = (int*)carve(NTOT * 4);
  int*   rowptr = (int*)carve((NTOT + 1) * 4);
  int*   colv   = (int*)carve(NE * 4);                // 0.79 MB
  if (off > ws_size) return;  // workspace too small: fail cleanly (out stays 0)

  hipMemsetAsync(deg, 0, NTOT * 4, stream);
  hipMemsetAsync(cursor, 0, NTOT * 4, stream);

  k_feat<<<(NTOT * 64) / 256, 256, 0, stream>>>(emb, nmask, nodeidx, h);
  k_wcat<<<(512 * 768) / 256, 256, 0, stream>>>(Wz, Uz, Wr, Ur, Wn, bz, br, bn, Wcat, bcat);
  k_count<<<NE / 256, 256, 0, stream>>>(edst, deg);
  k_scan<<<1, 256, 0, stream>>>(deg, rowptr);
  k_scatter<<<NE / 256, 256, 0, stream>>>(esrc, edst, rowptr, cursor, colv);

  for (int t = 0; t < 6; t++) {
    if (t == 0) {
      k_gemm<0><<<dim3(4, 192), 256, 0, stream>>>(h, W, Wh, nullptr, nullptr, nullptr,
                                                  12288, 256, 256, 0);
      k_esed<<<(12288 * 64) / 256, 256, 0, stream>>>(Wh, a_src, a_dst, es, ed, 12288, 0, 1);
    } else {
      // update Wh/es/ed for rows changed by last turn's GRU (turn t-1 rows)
      k_gemm<1><<<dim3(4, 32), 256, 0, stream>>>(h, W, Wh, nullptr, nullptr, nullptr,
                                                 2048, 256, 256, t - 1);
      k_esed<<<(2048 * 64) / 256, 256, 0, stream>>>(Wh, a_src, a_dst, es, ed, 2048, t - 1, 0);
    }
    if (t < 5)
      k_attn<<<(2048 * 64) / 256, 256, 0, stream>>>(rowptr, colv, es, ed, Wh, msg, score, t, 0);
    else
      k_attn<<<(12288 * 64) / 256, 256, 0, stream>>>(rowptr, colv, es, ed, Wh, msg, score, t, 1);
    k_gemm<2><<<dim3(12, 32), 256, 0, stream>>>(msg, Wcat, g1, h, bcat, nullptr,
                                                2048, 768, 512, t);
    k_rh<<<2048, 256, 0, stream>>>(g1, h, rh, t);
    k_gemm<3><<<dim3(4, 32), 256, 0, stream>>>(rh, Un, nullptr, h, nullptr, g1,
                                               2048, 256, 256, t);
  }

  k_pool<<<96, 256, 0, stream>>>(score, h, pooled);
  k_out<<<32, 256, 0, stream>>>(pooled, out);
}

// Round 4
// 847.633 us; speedup vs baseline: 1.0217x; 1.0217x over previous
//
#include <hip/hip_runtime.h>

#define NTOT 12288
#define NE   196608
#define MAXDEG 64

// turn-local row r (0..2047) of turn t -> global node id
__device__ __forceinline__ int turn_row_map(int r, int t) {
  return (r >> 7) * 768 + t * 128 + (r & 127);
}

// ---------------- prep kernels ----------------
__global__ void k_feat(const float* __restrict__ emb, const float* __restrict__ nmask,
                       const int* __restrict__ nodeidx, float* __restrict__ h) {
  int i = blockIdx.x * blockDim.x + threadIdx.x;  // over NTOT*64 float4
  if (i >= NTOT * 64) return;
  int row = i >> 6;
  int src = nodeidx[row];
  float m = nmask[src];
  float4 v = ((const float4*)emb)[(size_t)src * 64 + (i & 63)];
  v.x *= m; v.y *= m; v.z *= m; v.w *= m;
  ((float4*)h)[i] = v;
}

// padded adjacency: adj[v*MAXDEG + j] = src of j-th incoming edge of v (u16 ids)
__global__ void k_adj(const int* __restrict__ esrc, const int* __restrict__ edst,
                      int* __restrict__ cnt, unsigned short* __restrict__ adj) {
  int e = blockIdx.x * blockDim.x + threadIdx.x;
  if (e >= NE) return;
  int d = edst[e];
  int pos = atomicAdd(&cnt[d], 1);
  if (pos < MAXDEG) adj[(size_t)d * MAXDEG + pos] = (unsigned short)esrc[e];
}

// ---------------- shared GEMM core: 64x64 tile, K-chunk 32, 4x4/thread ----------------
__device__ __forceinline__ void gemm_core(const float (*As)[68], const float (*Bs)[64],
                                          int tx, int ty, float acc[4][4]) {
  float a4[4], b4[4];
#pragma unroll
  for (int kk = 0; kk < 32; kk++) {
#pragma unroll
    for (int i = 0; i < 4; i++) a4[i] = As[kk][ty * 4 + i];
#pragma unroll
    for (int j = 0; j < 4; j++) b4[j] = Bs[kk][tx * 4 + j];
#pragma unroll
    for (int i = 0; i < 4; i++)
#pragma unroll
      for (int j = 0; j < 4; j++) acc[i][j] += a4[i] * b4[j];
  }
}

__device__ __forceinline__ void stage_a(float (*As)[68], int arow, int kq, float4 av, int half) {
  As[half * 16 + kq * 4 + 0][arow] = av.x;
  As[half * 16 + kq * 4 + 1][arow] = av.y;
  As[half * 16 + kq * 4 + 2][arow] = av.z;
  As[half * 16 + kq * 4 + 3][arow] = av.w;
}

// MODE 0: full Wh = h @ W, rows direct     (grid 4 x 192), fused es/ed
// MODE 1: Wh rows of turn t via map        (grid 4 x 32),  fused es/ed
// MODE 3: acc = rh @ Un (rh lives in g1 cols 256..511, lda=768); GRU epilogue -> h
template <int MODE>
__global__ void __launch_bounds__(256)
k_gemm(const float* __restrict__ A, const float* __restrict__ B0, float* __restrict__ C,
       float* hbuf, const float* __restrict__ g1,
       const float* __restrict__ asrc, const float* __restrict__ adst,
       float* __restrict__ es, float* __restrict__ ed, int t) {
  __shared__ float As[32][68];
  __shared__ float Bs[32][64];
  int tid = threadIdx.x;
  int bx = blockIdx.x, by = blockIdx.y;
  int tx = tid & 15, ty = tid >> 4;
  int arow = tid >> 2, kq = tid & 3;
  int gm = by * 64 + arow;
  float acc[4][4] = {};
  for (int k0 = 0; k0 < 256; k0 += 32) {
#pragma unroll
    for (int half = 0; half < 2; half++) {
      int k = k0 + half * 16 + kq * 4;
      float4 av;
      if constexpr (MODE == 0) {
        av = *(const float4*)(A + (size_t)gm * 256 + k);
      } else if constexpr (MODE == 1) {
        av = *(const float4*)(A + (size_t)turn_row_map(gm, t) * 256 + k);
      } else {  // MODE 3: A = g1 + 256, lda 768
        av = *(const float4*)(A + (size_t)gm * 768 + 256 + k);
      }
      stage_a(As, arow, kq, av, half);
      *(float4*)&Bs[half * 16 + ty][tx * 4] =
          *(const float4*)(B0 + (size_t)(k0 + half * 16 + ty) * 256 + bx * 64 + tx * 4);
    }
    __syncthreads();
    gemm_core(As, Bs, tx, ty, acc);
    __syncthreads();
  }
  int row0 = by * 64 + ty * 4, col0 = bx * 64 + tx * 4;
  if constexpr (MODE == 0 || MODE == 1) {
    // store Wh
#pragma unroll
    for (int i = 0; i < 4; i++) {
      int r = row0 + i;
      int v = (MODE == 0) ? r : turn_row_map(r, t);
#pragma unroll
      for (int j = 0; j < 4; j++) C[(size_t)v * 256 + col0 + j] = acc[i][j];
    }
    // fused es/ed: head = bx (64 cols per head), reduce over this block's 64 cols
    float as4[4], ad4[4], esp[4], edp[4];
#pragma unroll
    for (int j = 0; j < 4; j++) { as4[j] = asrc[col0 + j]; ad4[j] = adst[col0 + j]; }
#pragma unroll
    for (int i = 0; i < 4; i++) {
      float e1 = 0.f, e2 = 0.f;
#pragma unroll
      for (int j = 0; j < 4; j++) { e1 += acc[i][j] * as4[j]; e2 += acc[i][j] * ad4[j]; }
      esp[i] = e1; edp[i] = e2;
    }
#pragma unroll
    for (int m = 1; m < 16; m <<= 1) {
#pragma unroll
      for (int i = 0; i < 4; i++) {
        esp[i] += __shfl_xor(esp[i], m);
        edp[i] += __shfl_xor(edp[i], m);
      }
    }
    if (tx == 0) {
#pragma unroll
      for (int i = 0; i < 4; i++) {
        int r = row0 + i;
        int v = (MODE == 0) ? r : turn_row_map(r, t);
        es[v * 4 + bx] = esp[i];
        ed[v * 4 + bx] = edp[i];
      }
    }
  } else {  // MODE 3: GRU epilogue
#pragma unroll
    for (int i = 0; i < 4; i++) {
      int r = row0 + i;
      int v = turn_row_map(r, t);
#pragma unroll
      for (int j = 0; j < 4; j++) {
        int c = col0 + j;
        float zpre = g1[(size_t)r * 768 + c];
        float npre = g1[(size_t)r * 768 + 512 + c] + acc[i][j];
        float z = 1.f / (1.f + __expf(-zpre));
        float n = tanhf(npre);
        float hv = hbuf[(size_t)v * 256 + c];
        hbuf[(size_t)v * 256 + c] = (1.f - z) * hv + z * n;
      }
    }
  }
}

// GEMM2: gate pre-activations. Block bx: gate g=bx>>2 (0=z,1=r,2=n), cols (bx&3)*64+...
// A = [msg | h_t] (K=512 for z,r; K=256 for n since Un-part is handled in MODE 3).
// Epilogue: z -> g1[0..255]; r -> sigmoid()*h stored in g1[256..511]; n -> g1[512..767].
__global__ void __launch_bounds__(256)
k_gemm2(const float* __restrict__ msg, float* __restrict__ hbuf,
        const float* __restrict__ Wz, const float* __restrict__ Uz,
        const float* __restrict__ Wr, const float* __restrict__ Ur,
        const float* __restrict__ Wn,
        const float* __restrict__ bz, const float* __restrict__ br,
        const float* __restrict__ bn, float* __restrict__ g1, int t) {
  __shared__ float As[32][68];
  __shared__ float Bs[32][64];
  int tid = threadIdx.x;
  int bx = blockIdx.x, by = blockIdx.y;
  int g = bx >> 2;
  int tx = tid & 15, ty = tid >> 4;
  int arow = tid >> 2, kq = tid & 3;
  int gm = by * 64 + arow;
  int cg0 = (bx & 3) * 64 + tx * 4;  // col within gate (0..255)
  const float* Bw = (g == 0) ? Wz : (g == 1) ? Wr : Wn;
  const float* Bu = (g == 0) ? Uz : Ur;  // unused when g==2
  const float* bias = (g == 0) ? bz : (g == 1) ? br : bn;
  int K = (g == 2) ? 256 : 512;
  float acc[4][4] = {};
  for (int k0 = 0; k0 < K; k0 += 32) {
#pragma unroll
    for (int half = 0; half < 2; half++) {
      int k = k0 + half * 16 + kq * 4;
      float4 av;
      if (k < 256) av = *(const float4*)(msg + (size_t)gm * 256 + k);
      else         av = *(const float4*)(hbuf + (size_t)turn_row_map(gm, t) * 256 + (k - 256));
      stage_a(As, arow, kq, av, half);
      int kr = k0 + half * 16 + ty;
      const float* Bp = (kr < 256) ? (Bw + (size_t)kr * 256)
                                   : (Bu + (size_t)(kr - 256) * 256);
      *(float4*)&Bs[half * 16 + ty][tx * 4] = *(const float4*)(Bp + (bx & 3) * 64 + tx * 4);
    }
    __syncthreads();
    gemm_core(As, Bs, tx, ty, acc);
    __syncthreads();
  }
  int row0 = by * 64 + ty * 4;
#pragma unroll
  for (int i = 0; i < 4; i++) {
    int r = row0 + i;
    int v = turn_row_map(r, t);
#pragma unroll
    for (int j = 0; j < 4; j++) {
      int c = cg0 + j;
      float pre = acc[i][j] + bias[c];
      if (g == 0)      g1[(size_t)r * 768 + c] = pre;                  // zpre
      else if (g == 1) {                                               // rh = sigmoid(rpre)*h
        float rr = 1.f / (1.f + __expf(-pre));
        g1[(size_t)r * 768 + 256 + c] = rr * hbuf[(size_t)v * 256 + c];
      } else           g1[(size_t)r * 768 + 512 + c] = pre;            // npre (msg@Wn+bn)
    }
  }
}

// per-dst attention softmax + message; one wave per dst node.
__global__ void k_attn(const int* __restrict__ cnt, const unsigned short* __restrict__ adj,
                       const float* __restrict__ es, const float* __restrict__ ed,
                       const float* __restrict__ Wh, float* __restrict__ msg,
                       float* __restrict__ score, int t, int allnodes) {
  int w = (blockIdx.x * blockDim.x + threadIdx.x) >> 6;
  int nwaves = allnodes ? NTOT : 2048;
  if (w >= nwaves) return;
  int lane = threadIdx.x & 63;
  int head = lane >> 4;
  int v, mrow, storemsg;
  if (allnodes) {
    v = w;
    int bt = v >> 7;          // b*6+t
    int tt = bt % 6;
    storemsg = (tt == t);
    mrow = (bt / 6) * 128 + (v & 127);
  } else {
    v = turn_row_map(w, t);
    mrow = w;
    storemsg = 1;
  }
  int deg = cnt[v];
  if (deg > MAXDEG) deg = MAXDEG;
  const unsigned short* row = adj + (size_t)v * MAXDEG;
  float edv = ed[v * 4 + head];
  float m = -1e30f;
  for (int j = 0; j < deg; j++) {
    int s = row[j];
    float lg = es[s * 4 + head] + edv;
    lg = lg >= 0.f ? lg : 0.2f * lg;
    m = fmaxf(m, lg);
  }
  float den = 0.f;
  float4 acc = make_float4(0.f, 0.f, 0.f, 0.f);
  for (int j = 0; j < deg; j++) {
    int s = row[j];
    float lg = es[s * 4 + head] + edv;
    lg = lg >= 0.f ? lg : 0.2f * lg;
    float wg = __expf(lg - m);
    den += wg;
    if (storemsg) {
      float4 x = ((const float4*)Wh)[(size_t)s * 64 + lane];
      acc.x += wg * x.x; acc.y += wg * x.y; acc.z += wg * x.z; acc.w += wg * x.w;
    }
  }
  float inv = 1.f / (den + 1e-9f);
  if (storemsg) {
    float4 o = make_float4(acc.x * inv, acc.y * inv, acc.z * inv, acc.w * inv);
    ((float4*)msg)[(size_t)mrow * 64 + lane] = o;
  }
  if (allnodes) {
    float val = den * inv;
    val += __shfl_xor(val, 16);
    val += __shfl_xor(val, 32);
    if (lane == 0) score[v] = 0.25f * val;
  }
}

// one block per (b,t): softmax over 128 node scores, then weighted mean of h
__global__ void k_pool(const float* __restrict__ score, const float* __restrict__ h,
                       float* __restrict__ pooled) {
  __shared__ float a[128];
  __shared__ float sinv;
  int bt = blockIdx.x;
  int base = bt * 128;
  int tid = threadIdx.x;
  if (tid < 128) a[tid] = score[base + tid];
  __syncthreads();
  if (tid == 0) {
    float mx = a[0];
    for (int n = 1; n < 128; n++) mx = fmaxf(mx, a[n]);
    float s = 0.f;
    for (int n = 0; n < 128; n++) { float e = __expf(a[n] - mx); a[n] = e; s += e; }
    sinv = 1.f / (s * 128.f);
  }
  __syncthreads();
  float acc = 0.f;
  for (int n = 0; n < 128; n++) acc += a[n] * h[(size_t)(base + n) * 256 + tid];
  pooled[bt * 256 + tid] = acc * sinv;
}

__global__ void k_out(const float* __restrict__ pooled, float* __restrict__ out) {
  int i = blockIdx.x * blockDim.x + threadIdx.x;  // 8192
  if (i >= 8192) return;
  int spk = i >> 12, b = (i >> 8) & 15, c = i & 255;
  float s = 0.f;
  for (int t = spk; t < 6; t += 2) s += pooled[(b * 6 + t) * 256 + c];
  out[i] = s;
}

extern "C" void kernel_launch(void* const* d_in, const int* in_sizes, int n_in,
                              void* d_out, int out_size, void* d_ws, size_t ws_size,
                              hipStream_t stream) {
  const float* emb    = (const float*)d_in[0];
  const float* nmask  = (const float*)d_in[1];
  const float* W      = (const float*)d_in[2];
  const float* a_src  = (const float*)d_in[3];
  const float* a_dst  = (const float*)d_in[4];
  const float* Wz     = (const float*)d_in[5];
  const float* Uz     = (const float*)d_in[6];
  const float* Wr     = (const float*)d_in[7];
  const float* Ur     = (const float*)d_in[8];
  const float* Wn     = (const float*)d_in[9];
  const float* Un     = (const float*)d_in[10];
  const float* bz     = (const float*)d_in[11];
  const float* br     = (const float*)d_in[12];
  const float* bn     = (const float*)d_in[13];
  const int* nodeidx  = (const int*)d_in[14];
  const int* esrc     = (const int*)d_in[15];
  const int* edst     = (const int*)d_in[16];
  float* out = (float*)d_out;

  char* ws = (char*)d_ws;
  size_t off = 0;
  auto carve = [&](size_t bytes) { char* p = ws + off; off += (bytes + 255) & ~(size_t)255; return p; };
  float* h      = (float*)carve(NTOT * 256 * 4);        // 12.6 MB
  float* Wh     = (float*)carve(NTOT * 256 * 4);        // 12.6 MB
  float* es     = (float*)carve(NTOT * 4 * 4);
  float* ed     = (float*)carve(NTOT * 4 * 4);
  float* msg    = (float*)carve(2048 * 256 * 4);        // 2 MB
  float* g1     = (float*)carve(2048 * 768 * 4);        // 6 MB (z | r*h | npre)
  float* score  = (float*)carve(NTOT * 4);
  float* pooled = (float*)carve(96 * 256 * 4);
  int*   cnt    = (int*)carve(NTOT * 4);
  unsigned short* adj = (unsigned short*)carve((size_t)NTOT * MAXDEG * 2);  // 1.57 MB
  if (off > ws_size) return;  // fail cleanly if workspace too small

  hipMemsetAsync(cnt, 0, NTOT * 4, stream);
  k_feat<<<(NTOT * 64) / 256, 256, 0, stream>>>(emb, nmask, nodeidx, h);
  k_adj<<<NE / 256, 256, 0, stream>>>(esrc, edst, cnt, adj);

  for (int t = 0; t < 6; t++) {
    if (t == 0) {
      k_gemm<0><<<dim3(4, 192), 256, 0, stream>>>(h, W, Wh, nullptr, nullptr,
                                                  a_src, a_dst, es, ed, 0);
    } else {
      // refresh Wh/es/ed for rows changed by last turn's GRU (turn t-1)
      k_gemm<1><<<dim3(4, 32), 256, 0, stream>>>(h, W, Wh, nullptr, nullptr,
                                                 a_src, a_dst, es, ed, t - 1);
    }
    if (t < 5)
      k_attn<<<(2048 * 64) / 256, 256, 0, stream>>>(cnt, adj, es, ed, Wh, msg, score, t, 0);
    else
      k_attn<<<(NTOT * 64) / 256, 256, 0, stream>>>(cnt, adj, es, ed, Wh, msg, score, t, 1);
    k_gemm2<<<dim3(12, 32), 256, 0, stream>>>(msg, h, Wz, Uz, Wr, Ur, Wn, bz, br, bn, g1, t);
    k_gemm<3><<<dim3(4, 32), 256, 0, stream>>>(g1, Un, nullptr, h, g1,
                                               nullptr, nullptr, nullptr, nullptr, t);
  }

  k_pool<<<96, 256, 0, stream>>>(score, h, pooled);
  k_out<<<32, 256, 0, stream>>>(pooled, out);
}

// Round 5
// 623.222 us; speedup vs baseline: 1.3896x; 1.3601x over previous
//
#include <hip/hip_runtime.h>

#define NTOT 12288
#define NE   196608
#define MAXDEG 64

// turn-local row r (0..2047) of turn t -> global node id
__device__ __forceinline__ int turn_row_map(int r, int t) {
  return (r >> 7) * 768 + t * 128 + (r & 127);
}

// ---------------- prep kernels ----------------
__global__ void k_feat(const float* __restrict__ emb, const float* __restrict__ nmask,
                       const int* __restrict__ nodeidx, float* __restrict__ h) {
  int i = blockIdx.x * blockDim.x + threadIdx.x;  // over NTOT*64 float4
  if (i >= NTOT * 64) return;
  int row = i >> 6;
  int src = nodeidx[row];
  float m = nmask[src];
  float4 v = ((const float4*)emb)[(size_t)src * 64 + (i & 63)];
  v.x *= m; v.y *= m; v.z *= m; v.w *= m;
  ((float4*)h)[i] = v;
}

// padded adjacency: adj[v*MAXDEG + j] = src of j-th incoming edge of v (u16 ids)
__global__ void k_adj(const int* __restrict__ esrc, const int* __restrict__ edst,
                      int* __restrict__ cnt, unsigned short* __restrict__ adj) {
  int e = blockIdx.x * blockDim.x + threadIdx.x;
  if (e >= NE) return;
  int d = edst[e];
  int pos = atomicAdd(&cnt[d], 1);
  if (pos < MAXDEG) adj[(size_t)d * MAXDEG + pos] = (unsigned short)esrc[e];
}

// ---------------- GEMM0: full Wh = h @ W (64x64 tile), fused es/ed ----------------
// 1-D grid 768; decode: bx=(l&31)>>3 (0..3), by=(l>>5)*8+(l&7) (0..191)  [XCD=by%8]
__global__ void __launch_bounds__(256)
k_gemm0(const float* __restrict__ A, const float* __restrict__ B0, float* __restrict__ C,
        const float* __restrict__ asrc, const float* __restrict__ adst,
        float* __restrict__ es, float* __restrict__ ed) {
  __shared__ float As[32][68];
  __shared__ float Bs[32][68];
  int l = blockIdx.x;
  int bx = (l & 31) >> 3, by = (l >> 5) * 8 + (l & 7);
  int tid = threadIdx.x;
  int tx = tid & 15, ty = tid >> 4;
  int arow = tid >> 2, kq = tid & 3;
  int gm = by * 64 + arow;
  float acc[4][4] = {};
  for (int k0 = 0; k0 < 256; k0 += 32) {
#pragma unroll
    for (int half = 0; half < 2; half++) {
      int k = k0 + half * 16 + kq * 4;
      float4 av = *(const float4*)(A + (size_t)gm * 256 + k);
      As[half * 16 + kq * 4 + 0][arow] = av.x;
      As[half * 16 + kq * 4 + 1][arow] = av.y;
      As[half * 16 + kq * 4 + 2][arow] = av.z;
      As[half * 16 + kq * 4 + 3][arow] = av.w;
      *(float4*)&Bs[half * 16 + ty][tx * 4] =
          *(const float4*)(B0 + (size_t)(k0 + half * 16 + ty) * 256 + bx * 64 + tx * 4);
    }
    __syncthreads();
    float a4[4], b4[4];
#pragma unroll
    for (int kk = 0; kk < 32; kk++) {
#pragma unroll
      for (int i = 0; i < 4; i++) a4[i] = As[kk][ty * 4 + i];
#pragma unroll
      for (int j = 0; j < 4; j++) b4[j] = Bs[kk][tx * 4 + j];
#pragma unroll
      for (int i = 0; i < 4; i++)
#pragma unroll
        for (int j = 0; j < 4; j++) acc[i][j] += a4[i] * b4[j];
    }
    __syncthreads();
  }
  int row0 = by * 64 + ty * 4, col0 = bx * 64 + tx * 4;
#pragma unroll
  for (int i = 0; i < 4; i++)
#pragma unroll
    for (int j = 0; j < 4; j++) C[(size_t)(row0 + i) * 256 + col0 + j] = acc[i][j];
  // fused es/ed (head = bx)
  float as4[4], ad4[4], esp[4], edp[4];
#pragma unroll
  for (int j = 0; j < 4; j++) { as4[j] = asrc[col0 + j]; ad4[j] = adst[col0 + j]; }
#pragma unroll
  for (int i = 0; i < 4; i++) {
    float e1 = 0.f, e2 = 0.f;
#pragma unroll
    for (int j = 0; j < 4; j++) { e1 += acc[i][j] * as4[j]; e2 += acc[i][j] * ad4[j]; }
    esp[i] = e1; edp[i] = e2;
  }
#pragma unroll
  for (int m = 1; m < 16; m <<= 1)
#pragma unroll
    for (int i = 0; i < 4; i++) {
      esp[i] += __shfl_xor(esp[i], m);
      edp[i] += __shfl_xor(edp[i], m);
    }
  if (tx == 0)
#pragma unroll
    for (int i = 0; i < 4; i++) {
      es[(row0 + i) * 4 + bx] = esp[i];
      ed[(row0 + i) * 4 + bx] = edp[i];
    }
}

// ---------------- 32-row-tile GEMM family: 256 thr, 2x4 acc/thread ----------------
// MODE 1 (whup): Wh rows of turn t from hbuf via map; B=W; fused es/ed  grid 256
// MODE 2 (gates): A=[msg|h_t]; B per gate; epilogue z/rh/npre -> g1     grid 768
// MODE 3 (gru):  A=g1 cols 256..511 (lda 768); B=Un; GRU -> h           grid 256
template <int MODE>
__global__ void __launch_bounds__(256)
k_gemm32(const float* __restrict__ A, const float* __restrict__ B0, float* __restrict__ C,
         float* hbuf, float* __restrict__ g1,
         const float* __restrict__ Wz, const float* __restrict__ Uz,
         const float* __restrict__ Wr, const float* __restrict__ Ur,
         const float* __restrict__ Wn,
         const float* __restrict__ bz, const float* __restrict__ br,
         const float* __restrict__ bn,
         const float* __restrict__ asrc, const float* __restrict__ adst,
         float* __restrict__ es, float* __restrict__ ed, int t) {
  __shared__ float As[32][37];
  __shared__ float Bs[32][68];
  int l = blockIdx.x;
  int bx, by;
  if constexpr (MODE == 2) { bx = (l % 96) >> 3; by = (l / 96) * 8 + (l & 7); }
  else                     { bx = (l & 31) >> 3; by = (l >> 5) * 8 + (l & 7); }
  int tid = threadIdx.x;
  int tx = tid & 15, ty = tid >> 4;
  int arow = tid >> 3, kq = tid & 7;   // A stage: 32 rows x 8 float4
  int gm = by * 32 + arow;

  const float* Bw = nullptr; const float* Bu = nullptr; const float* bias = nullptr;
  int g = 0, K = 256;
  if constexpr (MODE == 2) {
    g = bx >> 2;
    Bw = (g == 0) ? Wz : (g == 1) ? Wr : Wn;
    Bu = (g == 0) ? Uz : Ur;
    bias = (g == 0) ? bz : (g == 1) ? br : bn;
    K = (g == 2) ? 256 : 512;
  }
  int cb = (MODE == 2) ? (bx & 3) : bx;  // 64-col block within 256

  float acc[2][4] = {};
  for (int k0 = 0; k0 < K; k0 += 32) {
    {
      int k = k0 + kq * 4;
      float4 av;
      if constexpr (MODE == 1) {
        av = *(const float4*)(hbuf + (size_t)turn_row_map(gm, t) * 256 + k);
      } else if constexpr (MODE == 2) {
        if (k < 256) av = *(const float4*)(A + (size_t)gm * 256 + k);
        else         av = *(const float4*)(hbuf + (size_t)turn_row_map(gm, t) * 256 + (k - 256));
      } else {
        av = *(const float4*)(A + (size_t)gm * 768 + 256 + k);
      }
      As[kq * 4 + 0][arow] = av.x;
      As[kq * 4 + 1][arow] = av.y;
      As[kq * 4 + 2][arow] = av.z;
      As[kq * 4 + 3][arow] = av.w;
    }
#pragma unroll
    for (int half = 0; half < 2; half++) {
      int kr = k0 + half * 16 + ty;
      const float* Bp;
      if constexpr (MODE == 2) {
        Bp = (kr < 256) ? (Bw + (size_t)kr * 256) : (Bu + (size_t)(kr - 256) * 256);
      } else {
        Bp = B0 + (size_t)kr * 256;
      }
      *(float4*)&Bs[half * 16 + ty][tx * 4] = *(const float4*)(Bp + cb * 64 + tx * 4);
    }
    __syncthreads();
    float a2[2], b4[4];
#pragma unroll
    for (int kk = 0; kk < 32; kk++) {
#pragma unroll
      for (int i = 0; i < 2; i++) a2[i] = As[kk][ty * 2 + i];
#pragma unroll
      for (int j = 0; j < 4; j++) b4[j] = Bs[kk][tx * 4 + j];
#pragma unroll
      for (int i = 0; i < 2; i++)
#pragma unroll
        for (int j = 0; j < 4; j++) acc[i][j] += a2[i] * b4[j];
    }
    __syncthreads();
  }
  int row0 = by * 32 + ty * 2;
  if constexpr (MODE == 1) {
    int col0 = bx * 64 + tx * 4;
#pragma unroll
    for (int i = 0; i < 2; i++) {
      int v = turn_row_map(row0 + i, t);
#pragma unroll
      for (int j = 0; j < 4; j++) C[(size_t)v * 256 + col0 + j] = acc[i][j];
    }
    float as4[4], ad4[4], esp[2], edp[2];
#pragma unroll
    for (int j = 0; j < 4; j++) { as4[j] = asrc[col0 + j]; ad4[j] = adst[col0 + j]; }
#pragma unroll
    for (int i = 0; i < 2; i++) {
      float e1 = 0.f, e2 = 0.f;
#pragma unroll
      for (int j = 0; j < 4; j++) { e1 += acc[i][j] * as4[j]; e2 += acc[i][j] * ad4[j]; }
      esp[i] = e1; edp[i] = e2;
    }
#pragma unroll
    for (int m = 1; m < 16; m <<= 1)
#pragma unroll
      for (int i = 0; i < 2; i++) {
        esp[i] += __shfl_xor(esp[i], m);
        edp[i] += __shfl_xor(edp[i], m);
      }
    if (tx == 0)
#pragma unroll
      for (int i = 0; i < 2; i++) {
        int v = turn_row_map(row0 + i, t);
        es[v * 4 + bx] = esp[i];
        ed[v * 4 + bx] = edp[i];
      }
  } else if constexpr (MODE == 2) {
#pragma unroll
    for (int i = 0; i < 2; i++) {
      int r = row0 + i;
      int v = turn_row_map(r, t);
#pragma unroll
      for (int j = 0; j < 4; j++) {
        int c = cb * 64 + tx * 4 + j;
        float pre = acc[i][j] + bias[c];
        if (g == 0)      g1[(size_t)r * 768 + c] = pre;                  // zpre
        else if (g == 1) {                                               // rh
          float rr = 1.f / (1.f + __expf(-pre));
          g1[(size_t)r * 768 + 256 + c] = rr * hbuf[(size_t)v * 256 + c];
        } else           g1[(size_t)r * 768 + 512 + c] = pre;            // npre
      }
    }
  } else {  // MODE 3: GRU epilogue
#pragma unroll
    for (int i = 0; i < 2; i++) {
      int r = row0 + i;
      int v = turn_row_map(r, t);
#pragma unroll
      for (int j = 0; j < 4; j++) {
        int c = bx * 64 + tx * 4 + j;
        float zpre = g1[(size_t)r * 768 + c];
        float npre = g1[(size_t)r * 768 + 512 + c] + acc[i][j];
        float z = 1.f / (1.f + __expf(-zpre));
        float n = tanhf(npre);
        float hv = hbuf[(size_t)v * 256 + c];
        hbuf[(size_t)v * 256 + c] = (1.f - z) * hv + z * n;
      }
    }
  }
}

// per-dst attention softmax + message; one wave per dst node.
// Block decode clusters same-graph blocks on one XCD: g = blk&15, j = blk>>4.
__global__ void k_attn(const int* __restrict__ cnt, const unsigned short* __restrict__ adj,
                       const float* __restrict__ es, const float* __restrict__ ed,
                       const float* __restrict__ Wh, float* __restrict__ msg,
                       float* __restrict__ score, int t, int allnodes) {
  int gph = blockIdx.x & 15, j = blockIdx.x >> 4;
  int w = (allnodes ? gph * 768 : gph * 128) + j * 4 + (threadIdx.x >> 6);
  int lane = threadIdx.x & 63;
  int head = lane >> 4;
  int v, mrow, storemsg;
  if (allnodes) {
    v = w;
    int bt = v >> 7;          // b*6+t
    int tt = bt % 6;
    storemsg = (tt == t);
    mrow = (bt / 6) * 128 + (v & 127);
  } else {
    v = turn_row_map(w, t);
    mrow = w;
    storemsg = 1;
  }
  int deg = cnt[v];
  if (deg > MAXDEG) deg = MAXDEG;
  const unsigned short* row = adj + (size_t)v * MAXDEG;
  float edv = ed[v * 4 + head];
  float m = -1e30f;
  for (int jj = 0; jj < deg; jj++) {
    int s = row[jj];
    float lg = es[s * 4 + head] + edv;
    lg = lg >= 0.f ? lg : 0.2f * lg;
    m = fmaxf(m, lg);
  }
  float den = 0.f;
  float4 acc = make_float4(0.f, 0.f, 0.f, 0.f);
  for (int jj = 0; jj < deg; jj++) {
    int s = row[jj];
    float lg = es[s * 4 + head] + edv;
    lg = lg >= 0.f ? lg : 0.2f * lg;
    float wg = __expf(lg - m);
    den += wg;
    if (storemsg) {
      float4 x = ((const float4*)Wh)[(size_t)s * 64 + lane];
      acc.x += wg * x.x; acc.y += wg * x.y; acc.z += wg * x.z; acc.w += wg * x.w;
    }
  }
  float inv = 1.f / (den + 1e-9f);
  if (storemsg) {
    float4 o = make_float4(acc.x * inv, acc.y * inv, acc.z * inv, acc.w * inv);
    ((float4*)msg)[(size_t)mrow * 64 + lane] = o;
  }
  if (allnodes) {
    float val = den * inv;
    val += __shfl_xor(val, 16);
    val += __shfl_xor(val, 32);
    if (lane == 0) score[v] = 0.25f * val;
  }
}

// one block per (b,t): softmax over 128 node scores, then weighted mean of h
__global__ void k_pool(const float* __restrict__ score, const float* __restrict__ h,
                       float* __restrict__ pooled) {
  __shared__ float a[128];
  __shared__ float sinv;
  int bt = blockIdx.x;
  int base = bt * 128;
  int tid = threadIdx.x;
  if (tid < 128) a[tid] = score[base + tid];
  __syncthreads();
  if (tid == 0) {
    float mx = a[0];
    for (int n = 1; n < 128; n++) mx = fmaxf(mx, a[n]);
    float s = 0.f;
    for (int n = 0; n < 128; n++) { float e = __expf(a[n] - mx); a[n] = e; s += e; }
    sinv = 1.f / (s * 128.f);
  }
  __syncthreads();
  float acc = 0.f;
  for (int n = 0; n < 128; n++) acc += a[n] * h[(size_t)(base + n) * 256 + tid];
  pooled[bt * 256 + tid] = acc * sinv;
}

__global__ void k_out(const float* __restrict__ pooled, float* __restrict__ out) {
  int i = blockIdx.x * blockDim.x + threadIdx.x;  // 8192
  if (i >= 8192) return;
  int spk = i >> 12, b = (i >> 8) & 15, c = i & 255;
  float s = 0.f;
  for (int t = spk; t < 6; t += 2) s += pooled[(b * 6 + t) * 256 + c];
  out[i] = s;
}

extern "C" void kernel_launch(void* const* d_in, const int* in_sizes, int n_in,
                              void* d_out, int out_size, void* d_ws, size_t ws_size,
                              hipStream_t stream) {
  const float* emb    = (const float*)d_in[0];
  const float* nmask  = (const float*)d_in[1];
  const float* W      = (const float*)d_in[2];
  const float* a_src  = (const float*)d_in[3];
  const float* a_dst  = (const float*)d_in[4];
  const float* Wz     = (const float*)d_in[5];
  const float* Uz     = (const float*)d_in[6];
  const float* Wr     = (const float*)d_in[7];
  const float* Ur     = (const float*)d_in[8];
  const float* Wn     = (const float*)d_in[9];
  const float* Un     = (const float*)d_in[10];
  const float* bz     = (const float*)d_in[11];
  const float* br     = (const float*)d_in[12];
  const float* bn     = (const float*)d_in[13];
  const int* nodeidx  = (const int*)d_in[14];
  const int* esrc     = (const int*)d_in[15];
  const int* edst     = (const int*)d_in[16];
  float* out = (float*)d_out;

  char* ws = (char*)d_ws;
  size_t off = 0;
  auto carve = [&](size_t bytes) { char* p = ws + off; off += (bytes + 255) & ~(size_t)255; return p; };
  float* h      = (float*)carve(NTOT * 256 * 4);        // 12.6 MB
  float* Wh     = (float*)carve(NTOT * 256 * 4);        // 12.6 MB
  float* es     = (float*)carve(NTOT * 4 * 4);
  float* ed     = (float*)carve(NTOT * 4 * 4);
  float* msg    = (float*)carve(2048 * 256 * 4);        // 2 MB
  float* g1     = (float*)carve(2048 * 768 * 4);        // 6 MB (z | r*h | npre)
  float* score  = (float*)carve(NTOT * 4);
  float* pooled = (float*)carve(96 * 256 * 4);
  int*   cnt    = (int*)carve(NTOT * 4);
  unsigned short* adj = (unsigned short*)carve((size_t)NTOT * MAXDEG * 2);  // 1.57 MB
  if (off > ws_size) return;  // fail cleanly if workspace too small

  hipMemsetAsync(cnt, 0, NTOT * 4, stream);
  k_feat<<<(NTOT * 64) / 256, 256, 0, stream>>>(emb, nmask, nodeidx, h);
  k_adj<<<NE / 256, 256, 0, stream>>>(esrc, edst, cnt, adj);

  for (int t = 0; t < 6; t++) {
    if (t == 0) {
      k_gemm0<<<768, 256, 0, stream>>>(h, W, Wh, a_src, a_dst, es, ed);
    } else {
      k_gemm32<1><<<256, 256, 0, stream>>>(nullptr, W, Wh, h, nullptr,
                                           nullptr, nullptr, nullptr, nullptr, nullptr,
                                           nullptr, nullptr, nullptr,
                                           a_src, a_dst, es, ed, t - 1);
    }
    if (t < 5)
      k_attn<<<512, 256, 0, stream>>>(cnt, adj, es, ed, Wh, msg, score, t, 0);
    else
      k_attn<<<3072, 256, 0, stream>>>(cnt, adj, es, ed, Wh, msg, score, t, 1);
    k_gemm32<2><<<768, 256, 0, stream>>>(msg, nullptr, nullptr, h, g1,
                                         Wz, Uz, Wr, Ur, Wn, bz, br, bn,
                                         nullptr, nullptr, nullptr, nullptr, t);
    k_gemm32<3><<<256, 256, 0, stream>>>(g1, Un, nullptr, h, g1,
                                         nullptr, nullptr, nullptr, nullptr, nullptr,
                                         nullptr, nullptr, nullptr,
                                         nullptr, nullptr, nullptr, nullptr, t);
  }

  k_pool<<<96, 256, 0, stream>>>(score, h, pooled);
  k_out<<<32, 256, 0, stream>>>(pooled, out);
}